// Round 12
// baseline (119.066 us; speedup 1.0000x reference)
//
#include <hip/hip_runtime.h>

#define HH 512
#define DD 64

typedef unsigned short u16;
typedef short s16x8 __attribute__((ext_vector_type(8)));   // 8 bf16 = 4 VGPRs
typedef float f32x4 __attribute__((ext_vector_type(4)));

#define MFMA16(A,B,C) __builtin_amdgcn_mfma_f32_16x16x32_bf16((A),(B),(C),0,0,0)

// ---- weight layouts in d_ws (u16 element offsets; verified precompute) ----
// W2K/EFK k-major chunks: addr = chunk*16384 + nt*512 + lane*8
//   value[j] = M[k][n], k = chunk*32+(lane>>4)*8+j, n = nt*16+(lane&15)
// W1F: nt*1024 + ks*512 + lane*8 (K=64) ; W3F: ot*8192 + ks*512 + lane*8
#define OFF_W2K  0
#define OFF_EFK  262144
#define OFF_W1F  524288
#define OFF_W3F  557056
#define OFF_Z0B  (589824 * 2)
// ---- activation arrays (byte offsets) ----
// H1T/H2T/D2T: A-fragment-tiled bf16 [rowblk 64][chunk 16][rt 8][lane 64][8]
//   element (row, col): rowblk=row>>7, rt=(row>>4)&7, chunk=col>>5,
//   lane=(row&15)+16*((col&31)>>3), j=col&7 ; chunk-block stride 4096 u16
// D1: row-major bf16 [8192][512] ; PD: f32 [4][8192]
#define OFF_H1T_B (2u*1024*1024)
#define OFF_H2T_B (12u*1024*1024)
#define OFF_D2T_B (22u*1024*1024)
#define OFF_D1_B  (32u*1024*1024)
#define OFF_PD_B  (42u*1024*1024)

__device__ __forceinline__ u16 f2bf(float f) {
    unsigned u = __builtin_bit_cast(unsigned, f);
    u += 0x7fffu + ((u >> 16) & 1u);
    return (u16)(u >> 16);
}
__device__ __forceinline__ float bf2f(u16 h) {
    return __builtin_bit_cast(float, (unsigned)h << 16);
}
__device__ __forceinline__ float fast_tanh(float x) {
    float e = __expf(2.0f * x);
    return 1.0f - 2.0f * __builtin_amdgcn_rcpf(e + 1.0f);
}
__device__ __forceinline__ void gll(const u16* g, u16* l) {
    __builtin_amdgcn_global_load_lds(
        (const __attribute__((address_space(1))) unsigned int*)g,
        (__attribute__((address_space(3))) unsigned int*)l, 16, 0, 0);
}

// =======================================================================
// precompute: 137 blocks x 256 threads (verified; unchanged)
// =======================================================================
__global__ __launch_bounds__(256) void precompute(
    const float* __restrict__ t,  const float* __restrict__ W1,
    const float* __restrict__ b1, const float* __restrict__ W2,
    const float* __restrict__ W3, u16* __restrict__ ws16, float* __restrict__ z0)
{
    __shared__ float T[16 * 264 > 256 * 20 ? 16 * 264 : 256 * 20];
    u16* W2K = ws16 + OFF_W2K;
    u16* EFK = ws16 + OFF_EFK;
    u16* W1F = ws16 + OFF_W1F;
    u16* W3F = ws16 + OFF_W3F;

    const int bid = blockIdx.x, tid = threadIdx.x;
    const int lane = tid & 63, wv = tid >> 6;
    const int m16 = lane & 15, q = lane >> 4;

    if (bid < 64) {
        const int nt = bid >> 1, bh = bid & 1;
        const int a0 = nt * 16, b0 = bh * 256;
        s16x8 afh[2], afl[2];
#pragma unroll
        for (int h = 0; h < 2; ++h)
#pragma unroll
            for (int j = 0; j < 8; ++j) {
                int i = h * 32 + q * 8 + j;
                float v = W1[(1 + i) * HH + a0 + m16];
                u16 hi = f2bf(v);
                afh[h][j] = (short)hi;
                afl[h][j] = (short)f2bf(v - bf2f(hi));
            }
#pragma unroll
        for (int bt = 0; bt < 4; ++bt) {
            int bl = wv * 64 + bt * 16;
            s16x8 bfh[2], bfl[2];
#pragma unroll
            for (int h = 0; h < 2; ++h) {
                const float* src = W3 + (b0 + bl + m16) * DD + h * 32 + q * 8;
                float4 p0 = *(const float4*)(src);
                float4 p1 = *(const float4*)(src + 4);
                float vv[8] = {p0.x,p0.y,p0.z,p0.w,p1.x,p1.y,p1.z,p1.w};
#pragma unroll
                for (int j = 0; j < 8; ++j) {
                    u16 hi = f2bf(vv[j]);
                    bfh[h][j] = (short)hi;
                    bfl[h][j] = (short)f2bf(vv[j] - bf2f(hi));
                }
            }
            f32x4 c = {0.f, 0.f, 0.f, 0.f};
#pragma unroll
            for (int h = 0; h < 2; ++h) {
                c = MFMA16(afh[h], bfh[h], c);
                c = MFMA16(afh[h], bfl[h], c);
                c = MFMA16(afl[h], bfh[h], c);
            }
#pragma unroll
            for (int r = 0; r < 4; ++r)
                T[(4 * q + r) * 264 + bl + m16] = c[r];
        }
        __syncthreads();
#pragma unroll
        for (int p = 0; p < 2; ++p) {
            int ksl = p * 4 + wv;
            int al  = m16;
            int blc = ksl * 32 + q * 8;
            const float* w2p = W2 + (a0 + al) * HH + b0 + blc;
            float4 wa = *(const float4*)(w2p), wb = *(const float4*)(w2p + 4);
            const float* glp = T + al * 264 + blc;
            s16x8 o;
            o[0]=(short)f2bf(wa.x*glp[0]); o[1]=(short)f2bf(wa.y*glp[1]);
            o[2]=(short)f2bf(wa.z*glp[2]); o[3]=(short)f2bf(wa.w*glp[3]);
            o[4]=(short)f2bf(wb.x*glp[4]); o[5]=(short)f2bf(wb.y*glp[5]);
            o[6]=(short)f2bf(wb.z*glp[6]); o[7]=(short)f2bf(wb.w*glp[7]);
            *(s16x8*)(EFK + (b0 / 32 + ksl) * 16384 + nt * 512 + lane * 8) = o;
        }
        if (bh == 0 && tid < 128) {
            int ks = tid >> 6, ln = tid & 63;
            int n  = nt * 16 + (ln & 15);
            int k0 = ks * 32 + (ln >> 4) * 8;
            s16x8 o;
#pragma unroll
            for (int j = 0; j < 8; ++j) o[j] = (short)f2bf(W1[(1 + k0 + j) * HH + n]);
            *(s16x8*)(W1F + nt * 1024 + ks * 512 + ln * 8) = o;
        }
    } else if (bid < 128) {
        const int nt = (bid - 64) >> 1, kh = (bid - 64) & 1;
        const int n0 = nt * 16, k0 = kh * 256;
#pragma unroll
        for (int it = 0; it < 4; ++it) {
            int r = (tid >> 2) + it * 64;
            int c = (tid & 3) * 4;
            float4 v = *(const float4*)(W2 + (k0 + r) * HH + n0 + c);
            *(float4*)(T + r * 20 + c) = v;
        }
        __syncthreads();
#pragma unroll
        for (int p = 0; p < 2; ++p) {
            int ksl = p * 4 + wv;
            int kqx = ksl * 32 + q * 8;
            s16x8 o;
#pragma unroll
            for (int j = 0; j < 8; ++j) o[j] = (short)f2bf(T[(kqx + j) * 20 + m16]);
            *(s16x8*)(W2K + (k0 / 32 + ksl) * 16384 + nt * 512 + lane * 8) = o;
        }
    } else if (bid < 136) {
        const int ot = (bid - 128) >> 1, kh = (bid - 128) & 1;
        const int o0 = ot * 16, k0 = kh * 256;
#pragma unroll
        for (int it = 0; it < 4; ++it) {
            int r = (tid >> 2) + it * 64;
            int c = (tid & 3) * 4;
            float4 v = *(const float4*)(W3 + (k0 + r) * DD + o0 + c);
            *(float4*)(T + r * 20 + c) = v;
        }
        __syncthreads();
#pragma unroll
        for (int p = 0; p < 2; ++p) {
            int ksl = p * 4 + wv;
            int kqx = ksl * 32 + q * 8;
            s16x8 o;
#pragma unroll
            for (int j = 0; j < 8; ++j) o[j] = (short)f2bf(T[(kqx + j) * 20 + m16]);
            *(s16x8*)(W3F + ot * 8192 + (k0 / 32 + ksl) * 512 + lane * 8) = o;
        }
    } else {
        for (int n = tid; n < HH; n += 256)
            z0[n] = b1[n] + t[0] * W1[n];
    }
}

// =======================================================================
// K1: h1 = tanh([t,x]@W1 + z0) -> H1T (A-tiled) ; d1 -> D1 (row-major bf16)
// 256 blocks x 512 threads, 32 rows/block (R11 phase-1 core, verified)
// =======================================================================
__global__ __launch_bounds__(512) void k1_h1(
    const float* __restrict__ x, const u16* __restrict__ ws16,
    const float* __restrict__ z0, u16* __restrict__ h1t, u16* __restrict__ d1)
{
    __shared__ u16 h1s[32 * 520];
    __shared__ u16 xs[32 * 72];
    __shared__ float z0s[HH];

    const u16* W1F = ws16 + OFF_W1F;
    const int tid = threadIdx.x, lane = tid & 63, w = tid >> 6;
    const int m16 = lane & 15, q = lane >> 4, kq = q * 8;
    const int r0 = blockIdx.x * 32;

    for (int idx = tid; idx < 32 * DD; idx += 512) {
        int r = idx >> 6, c = idx & 63;
        xs[r * 72 + c] = f2bf(x[(r0 + r) * (DD + 1) + c]);
    }
    z0s[tid] = z0[tid];
    s16x8 b1f[4][2];
#pragma unroll
    for (int j = 0; j < 4; ++j) {
        const u16* bb = W1F + (4 * w + j) * 1024 + lane * 8;
        b1f[j][0] = *(const s16x8*)(bb);
        b1f[j][1] = *(const s16x8*)(bb + 512);
    }
    __syncthreads();

    {
        s16x8 xa[2][2];
#pragma unroll
        for (int rt = 0; rt < 2; ++rt) {
            xa[rt][0] = *(const s16x8*)(xs + (rt * 16 + m16) * 72 + kq);
            xa[rt][1] = *(const s16x8*)(xs + (rt * 16 + m16) * 72 + 32 + kq);
        }
#pragma unroll
        for (int j = 0; j < 4; ++j) {
            int col = (4 * w + j) * 16 + m16;
#pragma unroll
            for (int rt = 0; rt < 2; ++rt) {
                f32x4 c = {0.f, 0.f, 0.f, 0.f};
                c = MFMA16(xa[rt][0], b1f[j][0], c);
                c = MFMA16(xa[rt][1], b1f[j][1], c);
#pragma unroll
                for (int i = 0; i < 4; ++i) {
                    float hv = fast_tanh(c[i] + z0s[col]);
                    h1s[(rt * 16 + 4 * q + i) * 520 + col] = f2bf(hv);
                    d1[(r0 + rt * 16 + 4 * q + i) * HH + col] = f2bf(1.0f - hv * hv);
                }
            }
        }
    }
    __syncthreads();

    // frag-restore -> H1T
    const int rowblk = blockIdx.x >> 2;
#pragma unroll
    for (int p = 0; p < 2; ++p) {
        int ch = 2 * w + p;
#pragma unroll
        for (int rt = 0; rt < 2; ++rt) {
            int rtg = (blockIdx.x & 3) * 2 + rt;
            s16x8 f = *(const s16x8*)(h1s + (rt * 16 + m16) * 520 + ch * 32 + kq);
            *(s16x8*)(h1t + (rowblk * 16 + ch) * 4096 + rtg * 512 + lane * 8) = f;
        }
    }
}

// =======================================================================
// K2: h2 = tanh(h1@W2 + b2) -> H2T ; d2 = 1-h2^2 -> D2T  (m97-shape GEMM)
// 256 blocks x 256 threads (4 waves), C-tile 128 rows x 128 cols
// =======================================================================
__global__ __launch_bounds__(256) void k2_h2(
    const u16* __restrict__ ws16, const u16* __restrict__ h1t,
    const float* __restrict__ b2, u16* __restrict__ h2t, u16* __restrict__ d2t)
{
    __shared__ u16 smem[16384];   // 2 bufs x (A 4096 + B 4096); bounce reuses [0..8703]

    const u16* W2K = ws16 + OFF_W2K;
    const int tid = threadIdx.x, lane = tid & 63, w = tid >> 6;   // 4 waves
    const int m16 = lane & 15, q = lane >> 4, kq = q * 8;
    const int rowblk = blockIdx.x >> 2, ng = blockIdx.x & 3;
    const int rh = w >> 1, nh = w & 1;

    const u16* habase = h1t + rowblk * 16 * 4096;

    // prestage chunk 0 (each wave: 2 A-rts + 2 B-nts)
#pragma unroll
    for (int s = 0; s < 2; ++s) {
        gll(habase + (w + 4 * s) * 512 + lane * 8, smem + (w + 4 * s) * 512);
        gll(W2K + (ng * 8 + w + 4 * s) * 512 + lane * 8, smem + 4096 + (w + 4 * s) * 512);
    }
    __syncthreads();

    f32x4 acc[4][4];
#pragma unroll
    for (int rt = 0; rt < 4; ++rt)
#pragma unroll
        for (int nt = 0; nt < 4; ++nt) acc[rt][nt] = f32x4{0.f, 0.f, 0.f, 0.f};

    for (int c = 0; c < 16; ++c) {
        u16* cur = smem + (c & 1) * 8192;
        if (c < 15) {
            u16* nxt = smem + ((c + 1) & 1) * 8192;
#pragma unroll
            for (int s = 0; s < 2; ++s) {
                gll(habase + (c + 1) * 4096 + (w + 4 * s) * 512 + lane * 8,
                    nxt + (w + 4 * s) * 512);
                gll(W2K + (c + 1) * 16384 + (ng * 8 + w + 4 * s) * 512 + lane * 8,
                    nxt + 4096 + (w + 4 * s) * 512);
            }
        }
        s16x8 af[4], bf[4];
#pragma unroll
        for (int t = 0; t < 4; ++t) {
            af[t] = *(const s16x8*)(cur + (rh * 4 + t) * 512 + lane * 8);
            bf[t] = *(const s16x8*)(cur + 4096 + (nh * 4 + t) * 512 + lane * 8);
        }
#pragma unroll
        for (int rt = 0; rt < 4; ++rt)
#pragma unroll
            for (int nt = 0; nt < 4; ++nt)
                acc[rt][nt] = MFMA16(af[rt], bf[nt], acc[rt][nt]);
        __syncthreads();   // drains own-wave DMAs; publishes next buf; guards reuse
    }

    // epilogue: two 64-row half-passes through bounce (pitch 136)
    float b2v[4];
#pragma unroll
    for (int nt = 0; nt < 4; ++nt)
        b2v[nt] = b2[ng * 128 + (nh * 4 + nt) * 16 + m16];

    for (int hh = 0; hh < 2; ++hh) {
        if (rh == hh) {
#pragma unroll
            for (int rt = 0; rt < 4; ++rt)
#pragma unroll
                for (int nt = 0; nt < 4; ++nt)
#pragma unroll
                    for (int i = 0; i < 4; ++i)
                        smem[(rt * 16 + 4 * q + i) * 136 + (nh * 4 + nt) * 16 + m16] =
                            f2bf(fast_tanh(acc[rt][nt][i] + b2v[nt]));
        }
        __syncthreads();
        // frag-store: wave w -> rt_local w, 4 chunk-locals
#pragma unroll
        for (int chl = 0; chl < 4; ++chl) {
            s16x8 h = *(const s16x8*)(smem + (w * 16 + m16) * 136 + chl * 32 + kq);
            s16x8 d;
#pragma unroll
            for (int j = 0; j < 8; ++j) {
                float hv = bf2f((u16)h[j]);
                d[j] = (short)f2bf(1.0f - hv * hv);
            }
            int addr = (rowblk * 16 + ng * 4 + chl) * 4096 + (hh * 4 + w) * 512 + lane * 8;
            *(s16x8*)(h2t + addr) = h;
            *(s16x8*)(d2t + addr) = d;
        }
        __syncthreads();
    }
}

// =======================================================================
// K4: M = d2@Ef ; PD[ng][row] = sum over this block's 128 a-cols of d1.*M
// 256 blocks x 256 threads, same GEMM shape as K2
// =======================================================================
__global__ __launch_bounds__(256) void k4_div(
    const u16* __restrict__ ws16, const u16* __restrict__ d2t,
    const u16* __restrict__ d1, float* __restrict__ pd)
{
    __shared__ u16 smem[16384];
    __shared__ float divacc[2][128];

    const u16* EFK = ws16 + OFF_EFK;
    const int tid = threadIdx.x, lane = tid & 63, w = tid >> 6;
    const int m16 = lane & 15, q = lane >> 4;
    const int rowblk = blockIdx.x >> 2, ng = blockIdx.x & 3;
    const int rh = w >> 1, nh = w & 1;

    const u16* dabase = d2t + rowblk * 16 * 4096;

#pragma unroll
    for (int s = 0; s < 2; ++s) {
        gll(dabase + (w + 4 * s) * 512 + lane * 8, smem + (w + 4 * s) * 512);
        gll(EFK + (ng * 8 + w + 4 * s) * 512 + lane * 8, smem + 4096 + (w + 4 * s) * 512);
    }
    __syncthreads();

    f32x4 acc[4][4];
#pragma unroll
    for (int rt = 0; rt < 4; ++rt)
#pragma unroll
        for (int nt = 0; nt < 4; ++nt) acc[rt][nt] = f32x4{0.f, 0.f, 0.f, 0.f};

    for (int c = 0; c < 16; ++c) {
        u16* cur = smem + (c & 1) * 8192;
        if (c < 15) {
            u16* nxt = smem + ((c + 1) & 1) * 8192;
#pragma unroll
            for (int s = 0; s < 2; ++s) {
                gll(dabase + (c + 1) * 4096 + (w + 4 * s) * 512 + lane * 8,
                    nxt + (w + 4 * s) * 512);
                gll(EFK + (c + 1) * 16384 + (ng * 8 + w + 4 * s) * 512 + lane * 8,
                    nxt + 4096 + (w + 4 * s) * 512);
            }
        }
        s16x8 af[4], bf[4];
#pragma unroll
        for (int t = 0; t < 4; ++t) {
            af[t] = *(const s16x8*)(cur + (rh * 4 + t) * 512 + lane * 8);
            bf[t] = *(const s16x8*)(cur + 4096 + (nh * 4 + t) * 512 + lane * 8);
        }
#pragma unroll
        for (int rt = 0; rt < 4; ++rt)
#pragma unroll
            for (int nt = 0; nt < 4; ++nt)
                acc[rt][nt] = MFMA16(af[rt], bf[nt], acc[rt][nt]);
        __syncthreads();
    }

    // epilogue: v(row) = sum_nt d1[row, a] * M ; reduce over m16 lanes
#pragma unroll
    for (int rt = 0; rt < 4; ++rt)
#pragma unroll
        for (int i = 0; i < 4; ++i) {
            int row = rowblk * 128 + (rh * 4 + rt) * 16 + 4 * q + i;
            float v = 0.0f;
#pragma unroll
            for (int nt = 0; nt < 4; ++nt) {
                int col = ng * 128 + (nh * 4 + nt) * 16 + m16;
                v += bf2f(d1[row * HH + col]) * acc[rt][nt][i];
            }
            v += __shfl_xor(v, 1, 64);
            v += __shfl_xor(v, 2, 64);
            v += __shfl_xor(v, 4, 64);
            v += __shfl_xor(v, 8, 64);
            if (m16 == 0) divacc[nh][(rh * 4 + rt) * 16 + 4 * q + i] = v;
        }
    __syncthreads();
    if (tid < 128)
        pd[ng * 8192 + rowblk * 128 + tid] = divacc[0][tid] + divacc[1][tid];
}

// =======================================================================
// K3: dx = h2@W3 + b3 -> out cols 0..63 ; div = sum PD -> out col 64
// 256 blocks x 512 threads, 32 rows/block (register path; small weights)
// =======================================================================
__global__ __launch_bounds__(512) void k3_out(
    const u16* __restrict__ ws16, const u16* __restrict__ h2t,
    const float* __restrict__ b3, const float* __restrict__ pd,
    float* __restrict__ out)
{
    const u16* W3F = ws16 + OFF_W3F;
    const int tid = threadIdx.x, lane = tid & 63, w = tid >> 6;   // 8 waves
    const int m16 = lane & 15, q = lane >> 4;
    const int r0 = blockIdx.x * 32;
    const int rowblk = blockIdx.x >> 2;
    const int rtl = w >> 2, ot = w & 3;
    const int rtg = (blockIdx.x & 3) * 2 + rtl;

    const u16* ap = h2t + rowblk * 16 * 4096 + rtg * 512 + lane * 8;
    const u16* bp = W3F + ot * 8192 + lane * 8;

    f32x4 cA = {0.f,0.f,0.f,0.f}, cB = {0.f,0.f,0.f,0.f};
#pragma unroll
    for (int c = 0; c < 16; ++c) {
        s16x8 a = *(const s16x8*)(ap + c * 4096);
        s16x8 b = *(const s16x8*)(bp + c * 512);
        if (c & 1) cB = MFMA16(a, b, cB);
        else       cA = MFMA16(a, b, cA);
    }
    f32x4 c3 = cA + cB;
    int o = ot * 16 + m16;
    float b3v = b3[o];
#pragma unroll
    for (int i = 0; i < 4; ++i)
        out[(r0 + rtl * 16 + 4 * q + i) * (DD + 1) + o] = c3[i] + b3v;

    if (tid < 32) {
        int gr = r0 + tid;
        out[gr * (DD + 1) + DD] =
            pd[gr] + pd[8192 + gr] + pd[16384 + gr] + pd[24576 + gr];
    }
}

extern "C" void kernel_launch(void* const* d_in, const int* in_sizes, int n_in,
                              void* d_out, int out_size, void* d_ws, size_t ws_size,
                              hipStream_t stream) {
    const float* t  = (const float*)d_in[0];
    const float* x  = (const float*)d_in[1];
    const float* W1 = (const float*)d_in[2];
    const float* b1 = (const float*)d_in[3];
    const float* W2 = (const float*)d_in[4];
    const float* b2 = (const float*)d_in[5];
    const float* W3 = (const float*)d_in[6];
    const float* b3 = (const float*)d_in[7];
    float* out = (float*)d_out;

    u16*   ws16 = (u16*)d_ws;
    float* z0   = (float*)((char*)d_ws + OFF_Z0B);
    u16*   h1t  = (u16*)((char*)d_ws + OFF_H1T_B);
    u16*   h2t  = (u16*)((char*)d_ws + OFF_H2T_B);
    u16*   d2t  = (u16*)((char*)d_ws + OFF_D2T_B);
    u16*   d1   = (u16*)((char*)d_ws + OFF_D1_B);
    float* pd   = (float*)((char*)d_ws + OFF_PD_B);

    precompute<<<137, 256, 0, stream>>>(t, W1, b1, W2, W3, ws16, z0);
    k1_h1<<<256, 512, 0, stream>>>(x, ws16, z0, h1t, d1);
    k2_h2<<<256, 256, 0, stream>>>(ws16, h1t, b2, h2t, d2t);
    k4_div<<<256, 256, 0, stream>>>(ws16, d2t, d1, pd);
    k3_out<<<256, 512, 0, stream>>>(ws16, h2t, b3, pd, out);
}